// Round 5
// baseline (240.794 us; speedup 1.0000x reference)
//
#include <hip/hip_runtime.h>
#include <hip/hip_cooperative_groups.h>
#include <cstdint>
#include <cstddef>

namespace cg = cooperative_groups;

#define NPAIR 9216
#define BSTRIDE 98304   // 1024*96 floats per batch

typedef __attribute__((ext_vector_type(8))) short short8;
typedef __attribute__((ext_vector_type(4))) float f32x4;

__device__ __forceinline__ uint16_t f2bf(float x) {
    uint32_t u = __float_as_uint(x);
    return (uint16_t)((u + 0x7FFF + ((u >> 16) & 1)) >> 16);   // RNE
}
__device__ __forceinline__ float bf2f(uint16_t b) {
    return __uint_as_float(((uint32_t)b) << 16);
}

union Smem {
    struct { float zb[2][32][100]; float ps[2][32][3][2]; float stats[2][32][2]; } ln; // 27,648 B max
    struct { float T[64][17]; } kl;                                                    //  4,352 B
    struct { float red[2][2][64][25]; } r3;                                            // 25,600 B
};

// ======================= Phase 1 =======================
// blocks [0,128):   Z0 = x@M^T + LayerNorm -> Z  (64 rows/block, 2 groups of 32)
// blocks [128,144): Lt[t][s] = bf16(Linker[s][t])  (64 t-cols/block, x4 groups)
// blocks [144,256): Wt[s][p] basis via Chebyshev cos recurrence (grid-stride)
__device__ void phase1(Smem& sm, int bx, int t,
    const float* __restrict__ x, const float* __restrict__ M,
    const float* __restrict__ P, const float* __restrict__ L,
    const float* __restrict__ gamma, const float* __restrict__ beta,
    float* __restrict__ Z0, float* __restrict__ Z,
    uint16_t* __restrict__ Lt, uint16_t* __restrict__ Wt)
{
    if (bx < 128) {
        const int g = t >> 7, lt = t & 127;
        const int R0 = bx * 64 + g * 32;
        if (lt < 96) {
            float mreg[96];
            #pragma unroll
            for (int k4 = 0; k4 < 24; ++k4) {          // own M row, L1/L2-hot
                float4 v = *(const float4*)(M + lt * 96 + k4 * 4);
                mreg[k4*4+0]=v.x; mreg[k4*4+1]=v.y;
                mreg[k4*4+2]=v.z; mreg[k4*4+3]=v.w;
            }
            for (int r = 0; r < 32; ++r) {
                const float* xr = x + (size_t)(R0 + r) * 96;   // wave-uniform
                float a0 = 0.f, a1 = 0.f, a2 = 0.f, a3 = 0.f;
                #pragma unroll
                for (int j = 0; j < 96; j += 4) {
                    a0 = fmaf(xr[j+0], mreg[j+0], a0);
                    a1 = fmaf(xr[j+1], mreg[j+1], a1);
                    a2 = fmaf(xr[j+2], mreg[j+2], a2);
                    a3 = fmaf(xr[j+3], mreg[j+3], a3);
                }
                float z = (a0 + a1) + (a2 + a3);
                sm.ln.zb[g][r][lt] = z;
                Z0[(size_t)(R0 + r) * 96 + lt] = z;
            }
        }
        __syncthreads();
        if (lt < 96) {                 // segmented sums: 32 rows x 3 segs of 32
            int row = lt / 3, seg = lt % 3;
            const float4* zp = (const float4*)&sm.ln.zb[g][row][seg * 32];
            float s1 = 0.f, s2 = 0.f;
            #pragma unroll
            for (int k = 0; k < 8; ++k) {
                float4 v = zp[k];
                s1 += (v.x + v.y) + (v.z + v.w);
                s2 += (v.x*v.x + v.y*v.y) + (v.z*v.z + v.w*v.w);
            }
            sm.ln.ps[g][row][seg][0] = s1;
            sm.ln.ps[g][row][seg][1] = s2;
        }
        __syncthreads();
        if (lt < 32) {
            float s1 = sm.ln.ps[g][lt][0][0] + sm.ln.ps[g][lt][1][0] + sm.ln.ps[g][lt][2][0];
            float s2 = sm.ln.ps[g][lt][0][1] + sm.ln.ps[g][lt][1][1] + sm.ln.ps[g][lt][2][1];
            float mu  = s1 * (1.f / 96.f);
            float var = s2 * (1.f / 96.f) - mu * mu;
            sm.ln.stats[g][lt][0] = mu;
            sm.ln.stats[g][lt][1] = rsqrtf(var + 1e-5f);
        }
        __syncthreads();
        if (lt < 96) {
            float gm = gamma[lt], bt = beta[lt];
            for (int r = 0; r < 32; ++r) {
                float mu = sm.ln.stats[g][r][0], rs = sm.ln.stats[g][r][1];
                Z[(size_t)(R0 + r) * 96 + lt] = (sm.ln.zb[g][r][lt] - mu) * rs * gm + bt;
            }
        }
    } else if (bx < 144) {
        for (int cgi = 0; cgi < 4; ++cgi) {
            const int t0 = (bx - 128) * 64 + cgi * 16;
            const int tx = t & 15, ty = t >> 4;      // 16 x 16
            for (int s0 = 0; s0 < 1024; s0 += 64) {
                #pragma unroll
                for (int k = 0; k < 4; ++k) {
                    int sr = ty + k * 16;
                    sm.kl.T[sr][tx] = L[(size_t)(s0 + sr) * 1024 + t0 + tx];
                }
                __syncthreads();
                {
                    int trow = t >> 4, sc = (t & 15) * 4;
                    uint32_t u01 = (uint32_t)f2bf(sm.kl.T[sc+0][trow]) |
                                   ((uint32_t)f2bf(sm.kl.T[sc+1][trow]) << 16);
                    uint32_t u23 = (uint32_t)f2bf(sm.kl.T[sc+2][trow]) |
                                   ((uint32_t)f2bf(sm.kl.T[sc+3][trow]) << 16);
                    uint2 o; o.x = u01; o.y = u23;
                    *(uint2*)(Lt + (size_t)(t0 + trow) * 1024 + s0 + sc) = o;
                }
                __syncthreads();
            }
        }
    } else {
        // Chebyshev basis: unit = (p, 256-s chunk), reseed every 128 steps
        for (int u = (bx - 144) * 256 + t; u < 36864; u += 112 * 256) {
            const int p  = u % 9216;                 // = i*96 + j
            const int s0 = (u / 9216) * 256;
            const int base = p * 8;                  // period = base + g + 2
            float Pv[8], inv[8], tc1[8], c[8], cp[8];
            {
                float4 a = *(const float4*)(P + base);
                float4 b = *(const float4*)(P + base + 4);
                Pv[0]=a.x; Pv[1]=a.y; Pv[2]=a.z; Pv[3]=a.w;
                Pv[4]=b.x; Pv[5]=b.y; Pv[6]=b.z; Pv[7]=b.w;
            }
            #pragma unroll
            for (int g = 0; g < 8; ++g) {
                inv[g] = 1.0f / (float)(base + g + 2);
                float c1 = cospif(2.0f * inv[g]);
                tc1[g] = c1 + c1;
            }
            for (int half = 0; half < 2; ++half) {
                const int sh = s0 + half * 128;
                #pragma unroll
                for (int g = 0; g < 8; ++g) {
                    c[g]  = cospif(2.0f * (float)sh * inv[g]);
                    cp[g] = cospif(2.0f * (float)(sh - 1) * inv[g]);
                }
                uint16_t* op = Wt + (size_t)sh * NPAIR + p;
                for (int ss = 0; ss < 128; ++ss) {
                    float w = 0.f;
                    #pragma unroll
                    for (int g = 0; g < 8; ++g) w = fmaf(Pv[g], c[g], w);
                    *op = f2bf(w);
                    op += NPAIR;
                    #pragma unroll
                    for (int g = 0; g < 8; ++g) {
                        float cn = fmaf(tc1[g], c[g], -cp[g]);
                        cp[g] = c[g]; c[g] = cn;
                    }
                }
            }
        }
    }
}

// ======================= Phase 2 =======================
// Vt[b][i][s] = bf16( Z0[b,s,i] + sum_j Z[b,s,j]*Wt[s][i*96+j] ), 4 s/block
__device__ void phase2(int bx, int t,
    const float* __restrict__ Z, const float* __restrict__ Z0,
    const uint16_t* __restrict__ Wt, uint16_t* __restrict__ Vt)
{
    const int g = t >> 7, lt = t & 127;
    if (lt >= 96) return;
    const int i = lt;
    for (int it = 0; it < 2; ++it) {
        const int s = bx * 4 + g * 2 + it;
        float acc[8] = {0.f,0.f,0.f,0.f,0.f,0.f,0.f,0.f};
        const uint16_t* wrow = Wt + (size_t)s * NPAIR + i * 96;
        const float* zs = Z + (size_t)s * 96;        // wave-uniform base
        for (int j0 = 0; j0 < 96; j0 += 8) {
            short8 w8 = *(const short8*)(wrow + j0);
            float w[8];
            #pragma unroll
            for (int jj = 0; jj < 8; ++jj) w[jj] = bf2f((uint16_t)w8[jj]);
            #pragma unroll
            for (int bb = 0; bb < 8; ++bb) {
                const float* zbp = zs + (size_t)bb * BSTRIDE + j0;
                #pragma unroll
                for (int jj = 0; jj < 8; ++jj)
                    acc[bb] = fmaf(zbp[jj], w[jj], acc[bb]);
            }
        }
        #pragma unroll
        for (int bb = 0; bb < 8; ++bb) {
            size_t o = (size_t)bb * BSTRIDE + (size_t)s * 96 + i;
            Vt[((size_t)bb * 96 + i) * 1024 + s] = f2bf(acc[bb] + Z0[o]);
        }
    }
}

// ======================= Phase 3 =======================
// out[b,t,i] = sum_s Lt[t][s]*Vt[b][i][s].  2 tiles/block, K-split x2, LDS reduce.
__device__ void phase3(Smem& sm, int bx, int t,
    const uint16_t* __restrict__ Lt, const uint16_t* __restrict__ Vt,
    float* __restrict__ out)
{
    const int lane = t & 63;
    const int wv   = t >> 6;
    const int p    = wv >> 1;        // tile index within block
    const int h    = wv & 1;         // K half
    const int m    = lane & 15;
    const int quad = lane >> 4;
    const int tid  = bx * 2 + p;
    const int t0   = (tid >> 3) * 16;
    const int b    = tid & 7;

    const uint16_t* Lp = Lt + (size_t)(t0 + m) * 1024 + h * 512 + quad * 8;
    const uint16_t* Vp = Vt + ((size_t)b * 96 + m) * 1024 + h * 512 + quad * 8;

    f32x4 acc[6];
    #pragma unroll
    for (int ii = 0; ii < 6; ++ii) acc[ii] = (f32x4){0.f, 0.f, 0.f, 0.f};

    short8 a = *(const short8*)Lp;
    short8 bv[6];
    #pragma unroll
    for (int ii = 0; ii < 6; ++ii)
        bv[ii] = *(const short8*)(Vp + (size_t)ii * 16 * 1024);

    for (int kc = 0; kc < 15; ++kc) {                // 16 chunks of K=32
        short8 an = *(const short8*)(Lp + (kc + 1) * 32);
        short8 bn[6];
        #pragma unroll
        for (int ii = 0; ii < 6; ++ii)
            bn[ii] = *(const short8*)(Vp + (size_t)ii * 16 * 1024 + (kc + 1) * 32);
        #pragma unroll
        for (int ii = 0; ii < 6; ++ii)
            acc[ii] = __builtin_amdgcn_mfma_f32_16x16x32_bf16(a, bv[ii], acc[ii], 0, 0, 0);
        a = an;
        #pragma unroll
        for (int ii = 0; ii < 6; ++ii) bv[ii] = bn[ii];
    }
    #pragma unroll
    for (int ii = 0; ii < 6; ++ii)
        acc[ii] = __builtin_amdgcn_mfma_f32_16x16x32_bf16(a, bv[ii], acc[ii], 0, 0, 0);

    #pragma unroll
    for (int ii = 0; ii < 6; ++ii)
        #pragma unroll
        for (int r = 0; r < 4; ++r)
            sm.r3.red[p][h][lane][ii * 4 + r] = acc[ii][r];
    __syncthreads();
    {
        const int p2 = t >> 7, sub = (t >> 6) & 1, l2 = t & 63;
        const int m2 = l2 & 15, q2 = l2 >> 4;
        const int tid2 = bx * 2 + p2;
        const int t02 = (tid2 >> 3) * 16, b2 = tid2 & 7;
        #pragma unroll
        for (int k = sub * 12; k < sub * 12 + 12; ++k) {
            float sv = sm.r3.red[p2][0][l2][k] + sm.r3.red[p2][1][l2][k];
            int ii = k >> 2, r = k & 3;
            out[(size_t)b2 * BSTRIDE + (size_t)(t02 + q2 * 4 + r) * 96 + ii * 16 + m2] = sv;
        }
    }
}

// ======================= kernels =======================
__global__ __launch_bounds__(256, 2) void mega(
    const float* __restrict__ x, const float* __restrict__ M,
    const float* __restrict__ P, const float* __restrict__ L,
    const float* __restrict__ gamma, const float* __restrict__ beta,
    float* __restrict__ Z0, float* __restrict__ Z,
    uint16_t* __restrict__ Lt, uint16_t* __restrict__ Wt,
    uint16_t* __restrict__ Vt, float* __restrict__ out)
{
    cg::grid_group grid = cg::this_grid();
    __shared__ Smem sm;
    phase1(sm, blockIdx.x, threadIdx.x, x, M, P, L, gamma, beta, Z0, Z, Lt, Wt);
    grid.sync();
    phase2(blockIdx.x, threadIdx.x, Z, Z0, Wt, Vt);
    grid.sync();
    phase3(sm, blockIdx.x, threadIdx.x, Lt, Vt, out);
}

__global__ __launch_bounds__(256, 2) void kp1(
    const float* __restrict__ x, const float* __restrict__ M,
    const float* __restrict__ P, const float* __restrict__ L,
    const float* __restrict__ gamma, const float* __restrict__ beta,
    float* __restrict__ Z0, float* __restrict__ Z,
    uint16_t* __restrict__ Lt, uint16_t* __restrict__ Wt)
{
    __shared__ Smem sm;
    phase1(sm, blockIdx.x, threadIdx.x, x, M, P, L, gamma, beta, Z0, Z, Lt, Wt);
}
__global__ __launch_bounds__(256, 2) void kp2(
    const float* __restrict__ Z, const float* __restrict__ Z0,
    const uint16_t* __restrict__ Wt, uint16_t* __restrict__ Vt)
{
    phase2(blockIdx.x, threadIdx.x, Z, Z0, Wt, Vt);
}
__global__ __launch_bounds__(256, 2) void kp3(
    const uint16_t* __restrict__ Lt, const uint16_t* __restrict__ Vt,
    float* __restrict__ out)
{
    __shared__ Smem sm;
    phase3(sm, blockIdx.x, threadIdx.x, Lt, Vt, out);
}

extern "C" void kernel_launch(void* const* d_in, const int* in_sizes, int n_in,
                              void* d_out, int out_size, void* d_ws, size_t ws_size,
                              hipStream_t stream)
{
    const float* x     = (const float*)d_in[0];
    const float* M     = (const float*)d_in[1];
    const float* P     = (const float*)d_in[2];
    const float* Lnk   = (const float*)d_in[3];
    const float* gamma = (const float*)d_in[4];
    const float* beta  = (const float*)d_in[5];
    float* out = (float*)d_out;

    uint8_t* ws = (uint8_t*)d_ws;
    uint16_t* Wt = (uint16_t*)ws;                 // 18,874,368 B
    float*    Z0 = (float*)(ws + 18874368);       //  3,145,728 B
    float*    Z  = (float*)(ws + 22020096);       //  3,145,728 B
    uint16_t* Lt = (uint16_t*)(ws + 25165824);    //  2,097,152 B
    uint16_t* Vt = (uint16_t*)(ws + 27262976);    //  1,572,864 B  (~28.8 MB)

    int maxblk = 0;
    hipError_t qerr = hipOccupancyMaxActiveBlocksPerMultiprocessor(
        &maxblk, reinterpret_cast<const void*>(&mega), 256, 0);
    bool coop_done = false;
    if (qerr == hipSuccess && maxblk >= 1) {
        void* args[12] = { (void*)&x, (void*)&M, (void*)&P, (void*)&Lnk,
                           (void*)&gamma, (void*)&beta, (void*)&Z0, (void*)&Z,
                           (void*)&Lt, (void*)&Wt, (void*)&Vt, (void*)&out };
        hipError_t lerr = hipLaunchCooperativeKernel(
            reinterpret_cast<void*>(&mega), dim3(256), dim3(256), args, 0, stream);
        coop_done = (lerr == hipSuccess);
    }
    if (!coop_done) {
        kp1<<<256, 256, 0, stream>>>(x, M, P, Lnk, gamma, beta, Z0, Z, Lt, Wt);
        kp2<<<256, 256, 0, stream>>>(Z, Z0, Wt, Vt);
        kp3<<<256, 256, 0, stream>>>(Lt, Vt, out);
    }
}

// Round 6
// 125.224 us; speedup vs baseline: 1.9229x; 1.9229x over previous
//
#include <hip/hip_runtime.h>
#include <cstdint>
#include <cstddef>

#define NPAIR 9216
#define BSTRIDE 98304   // 1024*96 floats per batch

typedef __attribute__((ext_vector_type(8))) short short8;
typedef __attribute__((ext_vector_type(4))) float f32x4;

__device__ __forceinline__ uint16_t f2bf(float x) {
    uint32_t u = __float_as_uint(x);
    return (uint16_t)((u + 0x7FFF + ((u >> 16) & 1)) >> 16);   // RNE
}
__device__ __forceinline__ float bf2f(uint16_t b) {
    return __uint_as_float(((uint32_t)b) << 16);
}

// ---------------------------------------------------------------------------
// K1 mega-kernel, 96 threads/block, 2304 blocks (R3-proven structure):
//   blocks [0,512):    Z0 = x@M^T + fused LayerNorm -> Z   (16 rows/block)
//   blocks [512,768):  Lt[t][s] = bf16(Linker[s][t])       (64x64 tiles)
//   blocks [768,2304): Wt[s][j*96+i] via Chebyshev cos recurrence
//                      (i-contiguous row layout for kt coalescing)
// ---------------------------------------------------------------------------
union SmemK1 {
    float M[96][97];                                   // 37.2 KB (max)
    struct { float zb[16][100]; float ps[16][6][2]; float stats[16][2]; } ln;
    struct { float T[64][65]; } kl;
};

__global__ __launch_bounds__(96) void k1_mega(
    const float* __restrict__ x, const float* __restrict__ M,
    const float* __restrict__ P, const float* __restrict__ L,
    const float* __restrict__ gamma, const float* __restrict__ beta,
    float* __restrict__ Z0, float* __restrict__ Z,
    uint16_t* __restrict__ Lt, uint16_t* __restrict__ Wt)
{
    __shared__ SmemK1 sm;
    const int t  = threadIdx.x;
    const int bx = blockIdx.x;

    if (bx < 512) {
        // ---------------- proj + LN ----------------
        const int R0 = bx * 16;
        for (int k = 0; k < 24; ++k) {
            int mm = t + 96 * k;
            int i = mm / 24, j0 = (mm % 24) * 4;
            float4 v = *(const float4*)(M + i * 96 + j0);
            sm.M[i][j0]   = v.x; sm.M[i][j0+1] = v.y;
            sm.M[i][j0+2] = v.z; sm.M[i][j0+3] = v.w;
        }
        __syncthreads();
        float mreg[96];
        #pragma unroll
        for (int j = 0; j < 96; ++j) mreg[j] = sm.M[t][j];
        __syncthreads();   // M region dead; ln region reuses it

        for (int r = 0; r < 16; ++r) {
            const float* xr = x + (size_t)(R0 + r) * 96;  // wave-uniform
            float a0 = 0.f, a1 = 0.f, a2 = 0.f, a3 = 0.f;
            #pragma unroll
            for (int j = 0; j < 96; j += 4) {
                a0 = fmaf(xr[j+0], mreg[j+0], a0);
                a1 = fmaf(xr[j+1], mreg[j+1], a1);
                a2 = fmaf(xr[j+2], mreg[j+2], a2);
                a3 = fmaf(xr[j+3], mreg[j+3], a3);
            }
            float z = (a0 + a1) + (a2 + a3);
            sm.ln.zb[r][t] = z;
            Z0[(size_t)(R0 + r) * 96 + t] = z;
        }
        __syncthreads();
        {
            const int row = t / 6, seg = t % 6;
            const float4* zp = (const float4*)&sm.ln.zb[row][seg * 16];
            float s1 = 0.f, s2 = 0.f;
            #pragma unroll
            for (int k = 0; k < 4; ++k) {
                float4 v = zp[k];
                s1 += v.x + v.y + v.z + v.w;
                s2 += v.x*v.x + v.y*v.y + v.z*v.z + v.w*v.w;
            }
            sm.ln.ps[row][seg][0] = s1;
            sm.ln.ps[row][seg][1] = s2;
        }
        __syncthreads();
        if (t < 16) {
            float s1 = 0.f, s2 = 0.f;
            #pragma unroll
            for (int k = 0; k < 6; ++k) {
                s1 += sm.ln.ps[t][k][0];
                s2 += sm.ln.ps[t][k][1];
            }
            float mu  = s1 * (1.f / 96.f);
            float var = s2 * (1.f / 96.f) - mu * mu;
            sm.ln.stats[t][0] = mu;
            sm.ln.stats[t][1] = rsqrtf(var + 1e-5f);
        }
        __syncthreads();
        {
            float gm = gamma[t], bt = beta[t];
            for (int r = 0; r < 16; ++r) {
                float mu = sm.ln.stats[r][0], rs = sm.ln.stats[r][1];
                Z[(size_t)(R0 + r) * 96 + t] =
                    (sm.ln.zb[r][t] - mu) * rs * gm + bt;
            }
        }
        return;
    }

    if (bx < 768) {
        // ---------------- Linker transpose -> bf16 ----------------
        const int bx2 = bx - 512;
        const int s0 = (bx2 & 15) * 64, t0 = (bx2 >> 4) * 64;
        if (t < 64) {
            for (int r = 0; r < 64; ++r)
                sm.kl.T[r][t] = L[(size_t)(s0 + r) * 1024 + t0 + t];
        }
        __syncthreads();
        if (t < 64) {
            uint16_t* orow = Lt + (size_t)(t0 + t) * 1024 + s0;
            #pragma unroll
            for (int c4 = 0; c4 < 16; ++c4) {
                uint32_t u01 = (uint32_t)f2bf(sm.kl.T[c4*4+0][t]) |
                               ((uint32_t)f2bf(sm.kl.T[c4*4+1][t]) << 16);
                uint32_t u23 = (uint32_t)f2bf(sm.kl.T[c4*4+2][t]) |
                               ((uint32_t)f2bf(sm.kl.T[c4*4+3][t]) << 16);
                uint2 o; o.x = u01; o.y = u23;
                *(uint2*)(orow + c4 * 4) = o;
            }
        }
        return;
    }

    // ---------------- basis weights (Chebyshev over s) ----------------
    // element e = p = j*96 + i within row s; period from pair (i,j): base=(i*96+j)*8
    {
        const int idx = bx - 768;          // [0,1536)
        const int pb  = idx % 96;
        const int sc  = idx / 96;          // [0,16)
        const int p   = pb * 96 + t;       // element index in row = j*96+i
        const int i   = p % 96, j = p / 96;
        const int s0  = sc * 64;
        const int base = (i * 96 + j) * 8; // period = base + g + 2

        float Pv[8], c[8], cp[8], tc1[8];
        {
            float4 a = *(const float4*)(P + base);
            float4 b = *(const float4*)(P + base + 4);
            Pv[0]=a.x; Pv[1]=a.y; Pv[2]=a.z; Pv[3]=a.w;
            Pv[4]=b.x; Pv[5]=b.y; Pv[6]=b.z; Pv[7]=b.w;
        }
        #pragma unroll
        for (int g = 0; g < 8; ++g) {
            float inv = 1.0f / (float)(base + g + 2);
            float c1  = cospif(2.0f * inv);
            tc1[g] = c1 + c1;
            c[g]  = cospif(2.0f * (float)s0 * inv);
            cp[g] = cospif(2.0f * (float)(s0 - 1) * inv);
        }
        uint16_t* op = Wt + (size_t)s0 * NPAIR + p;
        for (int ss = 0; ss < 64; ++ss) {
            float w = 0.f;
            #pragma unroll
            for (int g = 0; g < 8; ++g) w = fmaf(Pv[g], c[g], w);
            *op = f2bf(w);
            op += NPAIR;
            #pragma unroll
            for (int g = 0; g < 8; ++g) {
                float cn = fmaf(tc1[g], c[g], -cp[g]);
                cp[g] = c[g]; c[g] = cn;
            }
        }
    }
}

// ---------------------------------------------------------------------------
// KT: Vt[b][i][s] = bf16( Z0[b,s,i] + sum_j Z[b,s,j]*Wt[s][j*96+i] )
// One block per s; lane = i.  Wt reads: per j the wave reads a contiguous
// 192 B span (lane-consecutive ushort) -> fully coalesced, no over-fetch.
// Z reads wave-uniform (scalar).
// ---------------------------------------------------------------------------
__global__ __launch_bounds__(96) void kt_apply(
    const float* __restrict__ Z, const float* __restrict__ Z0,
    const uint16_t* __restrict__ Wt, uint16_t* __restrict__ Vt)
{
    const int i = threadIdx.x;
    const int s = blockIdx.x;
    float acc[8] = {0.f,0.f,0.f,0.f,0.f,0.f,0.f,0.f};
    const uint16_t* wrow = Wt + (size_t)s * NPAIR + i;   // + j*96 per step
    const float* zs = Z + (size_t)s * 96;                // wave-uniform base
    #pragma unroll 8
    for (int j = 0; j < 96; ++j) {
        float w = bf2f(wrow[j * 96]);
        #pragma unroll
        for (int bb = 0; bb < 8; ++bb)
            acc[bb] = fmaf(zs[(size_t)bb * BSTRIDE + j], w, acc[bb]);
    }
    #pragma unroll
    for (int bb = 0; bb < 8; ++bb) {
        size_t o = (size_t)bb * BSTRIDE + (size_t)s * 96 + i;
        Vt[((size_t)bb * 96 + i) * 1024 + s] = f2bf(acc[bb] + Z0[o]);
    }
}

// ---------------------------------------------------------------------------
// K3: out[b,t,i] = sum_{s=0..1023} Lt[t][s]*Vt[b][i][s]
// MFMA 16x16x32 bf16, both operands K-major, full K per wave.
// 128 thr (2 waves, t-tile 32), grid (32, 8).  Depth-2 pipeline.
// ---------------------------------------------------------------------------
__global__ __launch_bounds__(128) void k3_mfma(
    const uint16_t* __restrict__ Lt, const uint16_t* __restrict__ Vt,
    float* __restrict__ out)
{
    const int lane = threadIdx.x & 63;
    const int wv   = threadIdx.x >> 6;
    const int m    = lane & 15;
    const int quad = lane >> 4;
    const int t0   = blockIdx.x * 32 + wv * 16;
    const int b    = blockIdx.y;

    const uint16_t* Lp = Lt + (size_t)(t0 + m) * 1024 + quad * 8;
    const uint16_t* Vp = Vt + ((size_t)b * 96 + m) * 1024 + quad * 8;

    f32x4 acc[6];
    #pragma unroll
    for (int ii = 0; ii < 6; ++ii) acc[ii] = (f32x4){0.f, 0.f, 0.f, 0.f};

    short8 a = *(const short8*)Lp;
    short8 bv[6];
    #pragma unroll
    for (int ii = 0; ii < 6; ++ii)
        bv[ii] = *(const short8*)(Vp + (size_t)ii * 16 * 1024);

    for (int kc = 0; kc < 31; ++kc) {
        short8 an = *(const short8*)(Lp + (kc + 1) * 32);
        short8 bn[6];
        #pragma unroll
        for (int ii = 0; ii < 6; ++ii)
            bn[ii] = *(const short8*)(Vp + (size_t)ii * 16 * 1024 + (kc + 1) * 32);
        #pragma unroll
        for (int ii = 0; ii < 6; ++ii)
            acc[ii] = __builtin_amdgcn_mfma_f32_16x16x32_bf16(a, bv[ii], acc[ii], 0, 0, 0);
        a = an;
        #pragma unroll
        for (int ii = 0; ii < 6; ++ii) bv[ii] = bn[ii];
    }
    #pragma unroll
    for (int ii = 0; ii < 6; ++ii)
        acc[ii] = __builtin_amdgcn_mfma_f32_16x16x32_bf16(a, bv[ii], acc[ii], 0, 0, 0);

    float* po = out + (size_t)b * BSTRIDE;
    #pragma unroll
    for (int ii = 0; ii < 6; ++ii)
        #pragma unroll
        for (int r = 0; r < 4; ++r)
            po[(size_t)(t0 + quad * 4 + r) * 96 + ii * 16 + m] = acc[ii][r];
}

extern "C" void kernel_launch(void* const* d_in, const int* in_sizes, int n_in,
                              void* d_out, int out_size, void* d_ws, size_t ws_size,
                              hipStream_t stream)
{
    const float* x     = (const float*)d_in[0];
    const float* M     = (const float*)d_in[1];
    const float* P     = (const float*)d_in[2];
    const float* Lnk   = (const float*)d_in[3];
    const float* gamma = (const float*)d_in[4];
    const float* beta  = (const float*)d_in[5];
    float* out = (float*)d_out;

    uint8_t* ws = (uint8_t*)d_ws;
    uint16_t* Wt = (uint16_t*)ws;                 // 18,874,368 B
    float*    Z0 = (float*)(ws + 18874368);       //  3,145,728 B
    float*    Z  = (float*)(ws + 22020096);       //  3,145,728 B
    uint16_t* Lt = (uint16_t*)(ws + 25165824);    //  2,097,152 B
    uint16_t* Vt = (uint16_t*)(ws + 27262976);    //  1,572,864 B  (~28.8 MB)

    k1_mega <<<2304, 96, 0, stream>>>(x, M, P, Lnk, gamma, beta, Z0, Z, Lt, Wt);
    kt_apply<<<1024, 96, 0, stream>>>(Z, Z0, Wt, Vt);
    k3_mfma <<<dim3(32, 8), 128, 0, stream>>>(Lt, Vt, out);
}